// Round 1
// baseline (515.314 us; speedup 1.0000x reference)
//
#include <hip/hip_runtime.h>

typedef short short8 __attribute__((ext_vector_type(8)));
typedef float f32x4 __attribute__((ext_vector_type(4)));

#define CST 3072  // cat row stride (6*512 channels)

__device__ __forceinline__ float bf2f(short s) {
  unsigned u = ((unsigned)(unsigned short)s) << 16;
  return __builtin_bit_cast(float, u);
}
__device__ __forceinline__ short f2bf(float f) {
  unsigned u = __builtin_bit_cast(unsigned, f);
  u = (u + 0x7FFFu + ((u >> 16) & 1u)) >> 16;
  return (short)u;
}

// ---- prep: scale_w -> bf16 (same [co][ci] layout = B-operand layout);
//      w_d reorder (27,512,3,3) -> wdr[di][o pad32][tap][c] bf16; zero stats.
__global__ void k_prep(const float* __restrict__ sw,
                       const float* __restrict__ w1, const float* __restrict__ w2,
                       const float* __restrict__ w3, const float* __restrict__ w4,
                       const float* __restrict__ w5,
                       short* __restrict__ wbf, short* __restrict__ wdr,
                       float* __restrict__ stats) {
  int idx = blockIdx.x * 256 + threadIdx.x;
  const int NS = 512 * 3072;
  const int NW = 5 * 32 * 9 * 512;
  if (idx < NS) {
    wbf[idx] = f2bf(sw[idx]);
  } else if (idx < NS + NW) {
    int j = idx - NS;
    int c = j & 511;
    int t2 = j >> 9;
    int tap = t2 % 9;
    int t3 = t2 / 9;
    int o = t3 & 31;
    int di = t3 >> 5;
    float v = 0.f;
    if (o < 27) {
      const float* wp = (di == 0) ? w1 : (di == 1) ? w2 : (di == 2) ? w3 : (di == 3) ? w4 : w5;
      v = wp[((o * 512 + c) * 3 + tap / 3) * 3 + tap % 3];
    }
    wdr[j] = f2bf(v);
  } else if (idx < NS + NW + 1024) {
    stats[idx - NS - NW] = 0.f;
  }
}

// ---- NCHW fp32 -> NHWC bf16 into cat channel-block 0 (row stride 3072)
__global__ __launch_bounds__(256) void k_transx(const float* __restrict__ x,
                                                short* __restrict__ cat) {
  __shared__ float tile[64][65];
  int b = blockIdx.x;
  int cblk = b & 7, h = (b >> 3) & 63, n = b >> 9;
  int c0 = cblk * 64;
  int t = threadIdx.x;
  int lw = t & 63, grp = t >> 6;
  const float* xp = x + (((size_t)n * 512 + c0) * 64 + h) * 64;
#pragma unroll
  for (int i = 0; i < 16; ++i) {
    int cl = grp * 16 + i;
    tile[cl][lw] = xp[(size_t)cl * 4096 + lw];
  }
  __syncthreads();
  int cl = t & 63;
  size_t mbase = ((size_t)n * 64 + h) * 64;
#pragma unroll
  for (int i = 0; i < 16; ++i) {
    int w = grp * 16 + i;
    cat[(mbase + w) * CST + c0 + cl] = f2bf(tile[cl][w]);
  }
}

// ---- fused per-dilation: offset-conv (MFMA) -> softmax -> deform sample
// block = 128 thr (2 waves) handles 16 positions (one m-tile).
// wave w computes fo cols [16w,16w+16); then each wave samples 8 positions.
__global__ __launch_bounds__(128) void k_dil(const short* __restrict__ xsrc,
                                             short* __restrict__ dst,
                                             const short* __restrict__ wdr,
                                             int d) {
  __shared__ float fo[16][33];
  __shared__ float filt[16][9];
  int m0 = blockIdx.x * 16;
  int tid = threadIdx.x;
  int wave = tid >> 6;
  int lane = tid & 63;
  int l15 = lane & 15, quad = lane >> 4;
  // ---------- conv ----------
  {
    int m = m0 + l15;
    int n = m >> 12, h = (m >> 6) & 63, w = m & 63;
    f32x4 acc = {0.f, 0.f, 0.f, 0.f};
    int ob = wave * 16;
    const short8 z8 = {0, 0, 0, 0, 0, 0, 0, 0};
#pragma unroll
    for (int tap = 0; tap < 9; ++tap) {
      int hh = h + (tap / 3 - 1) * d;
      if ((unsigned)hh >= 64u) continue;  // uniform across wave (h uniform in tile)
      int ww = w + (tap % 3 - 1) * d;
      bool ok = (unsigned)ww < 64u;
      int mrow = (n << 12) + (hh << 6) + (ok ? ww : w);  // safe addr when masked
      const short* arow = xsrc + (size_t)mrow * CST + quad * 8;
      const short* brow = wdr + ((ob + l15) * 9 + tap) * 512 + quad * 8;
#pragma unroll 4
      for (int ks = 0; ks < 16; ++ks) {
        short8 a = *(const short8*)(arow + ks * 32);
        if (!ok) a = z8;
        short8 b = *(const short8*)(brow + ks * 32);
        acc = __builtin_amdgcn_mfma_f32_16x16x32_bf16(a, b, acc, 0, 0, 0);
      }
    }
#pragma unroll
    for (int r = 0; r < 4; ++r) fo[quad * 4 + r][ob + l15] = acc[r];
  }
  __syncthreads();
  // ---------- softmax over 9 taps (16 positions, one thread each) ----------
  if (tid < 16) {
    int p = tid;
    float mx = fo[p][0];
#pragma unroll
    for (int k = 1; k < 9; ++k) mx = fmaxf(mx, fo[p][k]);
    float s = 0.f, e[9];
#pragma unroll
    for (int k = 0; k < 9; ++k) { e[k] = __expf(fo[p][k] - mx); s += e[k]; }
    float inv = 1.f / s;
#pragma unroll
    for (int k = 0; k < 9; ++k) filt[p][k] = e[k] * inv;
  }
  __syncthreads();
  // ---------- deform bilinear sample; lane = 8 contiguous channels ----------
#pragma unroll 1
  for (int i = 0; i < 8; ++i) {
    int p = wave * 8 + i;
    int m = m0 + p;
    int n = m >> 12, h = (m >> 6) & 63, w = m & 63;
    const short* xb = xsrc + (size_t)(n << 12) * CST + lane * 8;
    float acc[8] = {0.f, 0.f, 0.f, 0.f, 0.f, 0.f, 0.f, 0.f};
#pragma unroll 3
    for (int k = 0; k < 9; ++k) {
      float f = filt[p][k];
      float dy = fo[p][9 + 2 * k];
      float dx = fo[p][10 + 2 * k];
      float ys = (float)(h + (k / 3 - 1) * d) + dy;
      float xs = (float)(w + (k % 3 - 1) * d) + dx;
      float y0f = floorf(ys), x0f = floorf(xs);
      float wy1 = ys - y0f, wx1 = xs - x0f;
      float wy0 = 1.f - wy1, wx0 = 1.f - wx1;
      int y0 = (int)y0f, x0 = (int)x0f;
#pragma unroll
      for (int cy = 0; cy < 2; ++cy) {
#pragma unroll
        for (int cx = 0; cx < 2; ++cx) {
          int yy = y0 + cy, xx = x0 + cx;
          bool v = ((unsigned)yy < 64u) && ((unsigned)xx < 64u);
          float wt = f * (cy ? wy1 : wy0) * (cx ? wx1 : wx0);
          wt = v ? wt : 0.f;
          int row = v ? ((yy << 6) + xx) : 0;
          const short8 vv = *(const short8*)(xb + (size_t)row * CST);
#pragma unroll
          for (int j = 0; j < 8; ++j) acc[j] += wt * bf2f(vv[j]);
        }
      }
    }
    short8 o8;
#pragma unroll
    for (int j = 0; j < 8; ++j) o8[j] = f2bf(acc[j]);
    *(short8*)(dst + (size_t)m * CST + lane * 8) = o8;
  }
}

// ---- 1x1 fuse conv: Y[8192x512] = cat[8192x3072] * wbf^T, bf16 MFMA.
// block 256 = 4 waves, block tile 128x128, wave tile 64x64 (4x4 frags).
__global__ __launch_bounds__(256) void k_gemm(const short* __restrict__ A,
                                              const short* __restrict__ B,
                                              float* __restrict__ Y) {
  int tid = threadIdx.x;
  int wave = tid >> 6, lane = tid & 63;
  int l15 = lane & 15, quad = lane >> 4;
  int mw = blockIdx.x * 128 + (wave >> 1) * 64;
  int nw = blockIdx.y * 128 + (wave & 1) * 64;
  f32x4 acc[4][4];
  f32x4 zz = {0.f, 0.f, 0.f, 0.f};
#pragma unroll
  for (int i = 0; i < 4; ++i)
#pragma unroll
    for (int j = 0; j < 4; ++j) acc[i][j] = zz;
  const short* ap = A + (size_t)(mw + l15) * CST + quad * 8;
  const short* bp = B + (size_t)(nw + l15) * CST + quad * 8;
  for (int kb = 0; kb < 96; ++kb) {
    int k0 = kb * 32;
    short8 a[4], b[4];
#pragma unroll
    for (int i = 0; i < 4; ++i) a[i] = *(const short8*)(ap + (size_t)i * 16 * CST + k0);
#pragma unroll
    for (int j = 0; j < 4; ++j) b[j] = *(const short8*)(bp + (size_t)j * 16 * CST + k0);
#pragma unroll
    for (int i = 0; i < 4; ++i)
#pragma unroll
      for (int j = 0; j < 4; ++j)
        acc[i][j] = __builtin_amdgcn_mfma_f32_16x16x32_bf16(a[i], b[j], acc[i][j], 0, 0, 0);
  }
#pragma unroll
  for (int i = 0; i < 4; ++i) {
    int row = mw + i * 16 + quad * 4;
#pragma unroll
    for (int j = 0; j < 4; ++j) {
      int col = nw + j * 16 + l15;
#pragma unroll
      for (int r = 0; r < 4; ++r) Y[(size_t)(row + r) * 512 + col] = acc[i][j][r];
    }
  }
}

// ---- per-channel sum / sumsq over m (atomics after 32-row register accum)
__global__ __launch_bounds__(256) void k_stats(const float* __restrict__ Y,
                                               float* __restrict__ stats) {
  int tid = threadIdx.x;
  int mb = blockIdx.x * 32;
  float s0 = 0.f, q0 = 0.f, s1 = 0.f, q1 = 0.f;
  for (int r = 0; r < 32; ++r) {
    const float* row = Y + (size_t)(mb + r) * 512;
    float v0 = row[tid], v1 = row[tid + 256];
    s0 += v0; q0 += v0 * v0;
    s1 += v1; q1 += v1 * v1;
  }
  atomicAdd(&stats[tid], s0);
  atomicAdd(&stats[tid + 256], s1);
  atomicAdd(&stats[512 + tid], q0);
  atomicAdd(&stats[512 + tid + 256], q1);
}

// ---- normalize + NHWC->NCHW transpose -> d_out
__global__ __launch_bounds__(256) void k_norm(const float* __restrict__ Y,
                                              const float* __restrict__ stats,
                                              const float* __restrict__ gamma,
                                              const float* __restrict__ beta,
                                              float* __restrict__ out) {
  __shared__ float tile[64][65];
  int b = blockIdx.x;
  int cblk = b & 7, h = (b >> 3) & 63, n = b >> 9;
  int c0 = cblk * 64;
  int t = threadIdx.x;
  int cl = t & 63, grp = t >> 6;
  int c = c0 + cl;
  float mean = stats[c] * (1.f / 8192.f);
  float var = stats[512 + c] * (1.f / 8192.f) - mean * mean;
  float Ai = gamma[c] * rsqrtf(var + 1e-5f);
  float Bi = beta[c] - mean * Ai;
  size_t mbase = ((size_t)n * 64 + h) * 64;
#pragma unroll
  for (int i = 0; i < 16; ++i) {
    int w = grp * 16 + i;
    tile[w][cl] = Y[(mbase + w) * 512 + c] * Ai + Bi;
  }
  __syncthreads();
  float* op = out + (((size_t)n * 512 + c0) * 64 + h) * 64;
#pragma unroll
  for (int i = 0; i < 16; ++i) {
    int c2 = grp * 16 + i;
    op[(size_t)c2 * 4096 + cl] = tile[cl][c2];
  }
}

extern "C" void kernel_launch(void* const* d_in, const int* in_sizes, int n_in,
                              void* d_out, int out_size, void* d_ws, size_t ws_size,
                              hipStream_t stream) {
  const float* x  = (const float*)d_in[0];
  const float* w1 = (const float*)d_in[1];
  const float* w2 = (const float*)d_in[2];
  const float* w3 = (const float*)d_in[3];
  const float* w4 = (const float*)d_in[4];
  const float* w5 = (const float*)d_in[5];
  const float* sw = (const float*)d_in[6];
  const float* gamma = (const float*)d_in[7];
  const float* beta  = (const float*)d_in[8];
  float* out = (float*)d_out;

  char* ws = (char*)d_ws;
  // workspace layout (bytes):
  // cat   @ 0        : 8192*3072*2  = 50331648   (bf16, block0 = x NHWC)
  // wbf   @ 50331648 : 512*3072*2   = 3145728
  // wdr   @ 53477376 : 5*32*9*512*2 = 1474560
  // yb    @ 54951936 : 8192*512*4   = 16777216
  // stats @ 71729152 : 1024*4
  short* cat   = (short*)ws;
  short* wbf   = (short*)(ws + 50331648);
  short* wdr   = (short*)(ws + 53477376);
  float* yb    = (float*)(ws + 54951936);
  float* stats = (float*)(ws + 71729152);

  k_prep<<<9028, 256, 0, stream>>>(sw, w1, w2, w3, w4, w5, wbf, wdr, stats);
  k_transx<<<1024, 256, 0, stream>>>(x, cat);
  const int DIL[5] = {1, 6, 12, 24, 36};
  for (int di = 0; di < 5; ++di)
    k_dil<<<512, 128, 0, stream>>>(cat, cat + 512 * (di + 1),
                                   wdr + di * 32 * 9 * 512, DIL[di]);
  k_gemm<<<dim3(64, 4), 256, 0, stream>>>(cat, wbf, yb);
  k_stats<<<256, 256, 0, stream>>>(yb, stats);
  k_norm<<<1024, 256, 0, stream>>>(yb, stats, gamma, beta, out);
}

// Round 2
// 447.065 us; speedup vs baseline: 1.1527x; 1.1527x over previous
//
#include <hip/hip_runtime.h>

typedef short short8 __attribute__((ext_vector_type(8)));
typedef float f32x4 __attribute__((ext_vector_type(4)));

#define CST 3072  // cat row stride (6*512 channels)

__device__ __forceinline__ float bf2f(short s) {
  unsigned u = ((unsigned)(unsigned short)s) << 16;
  return __builtin_bit_cast(float, u);
}
__device__ __forceinline__ short f2bf(float f) {
  unsigned u = __builtin_bit_cast(unsigned, f);
  u = (u + 0x7FFFu + ((u >> 16) & 1u)) >> 16;
  return (short)u;
}

// ---- prep: scale_w -> bf16; w_d reorder (27,512,3,3) -> wdr[di][o pad32][tap][c]; zero stats.
__global__ void k_prep(const float* __restrict__ sw,
                       const float* __restrict__ w1, const float* __restrict__ w2,
                       const float* __restrict__ w3, const float* __restrict__ w4,
                       const float* __restrict__ w5,
                       short* __restrict__ wbf, short* __restrict__ wdr,
                       float* __restrict__ stats) {
  int idx = blockIdx.x * 256 + threadIdx.x;
  const int NS = 512 * 3072;
  const int NW = 5 * 32 * 9 * 512;
  if (idx < NS) {
    wbf[idx] = f2bf(sw[idx]);
  } else if (idx < NS + NW) {
    int j = idx - NS;
    int c = j & 511;
    int t2 = j >> 9;
    int tap = t2 % 9;
    int t3 = t2 / 9;
    int o = t3 & 31;
    int di = t3 >> 5;
    float v = 0.f;
    if (o < 27) {
      const float* wp = (di == 0) ? w1 : (di == 1) ? w2 : (di == 2) ? w3 : (di == 3) ? w4 : w5;
      v = wp[((o * 512 + c) * 3 + tap / 3) * 3 + tap % 3];
    }
    wdr[j] = f2bf(v);
  } else if (idx < NS + NW + 1024) {
    stats[idx - NS - NW] = 0.f;
  }
}

// ---- NCHW fp32 -> NHWC bf16 into cat channel-block 0 (row stride 3072)
__global__ __launch_bounds__(256) void k_transx(const float* __restrict__ x,
                                                short* __restrict__ cat) {
  __shared__ float tile[64][65];
  int b = blockIdx.x;
  int cblk = b & 7, h = (b >> 3) & 63, n = b >> 9;
  int c0 = cblk * 64;
  int t = threadIdx.x;
  int lw = t & 63, grp = t >> 6;
  const float* xp = x + (((size_t)n * 512 + c0) * 64 + h) * 64;
#pragma unroll
  for (int i = 0; i < 16; ++i) {
    int cl = grp * 16 + i;
    tile[cl][lw] = xp[(size_t)cl * 4096 + lw];
  }
  __syncthreads();
  int cl = t & 63;
  size_t mbase = ((size_t)n * 64 + h) * 64;
#pragma unroll
  for (int i = 0; i < 16; ++i) {
    int w = grp * 16 + i;
    cat[(mbase + w) * CST + c0 + cl] = f2bf(tile[cl][w]);
  }
}

// ---- fused per-dilation: offset-conv (MFMA) -> softmax -> deform sample.
// ALL 5 dilations in one launch: blockIdx.x = di*512 + tile. 2560 blocks
// of 128 thr -> ~10 blocks/CU (20 waves/CU) for latency hiding.
__global__ __launch_bounds__(128) void k_dil(const short* __restrict__ xsrc,
                                             short* __restrict__ cat,
                                             const short* __restrict__ wdr_all) {
  __shared__ float fo[16][33];
  __shared__ float filt[16][9];
  int bi = blockIdx.x;
  int di = bi >> 9;
  int m0 = (bi & 511) * 16;
  const int DIL[5] = {1, 6, 12, 24, 36};
  int d = DIL[di];
  short* dst = cat + 512 * (di + 1);
  const short* wdr = wdr_all + di * 32 * 9 * 512;

  int tid = threadIdx.x;
  int wave = tid >> 6;
  int lane = tid & 63;
  int l15 = lane & 15, quad = lane >> 4;
  // ---------- conv ----------
  {
    int m = m0 + l15;
    int n = m >> 12, h = (m >> 6) & 63, w = m & 63;
    f32x4 acc = {0.f, 0.f, 0.f, 0.f};
    int ob = wave * 16;
    const short8 z8 = {0, 0, 0, 0, 0, 0, 0, 0};
#pragma unroll
    for (int tap = 0; tap < 9; ++tap) {
      int hh = h + (tap / 3 - 1) * d;
      if ((unsigned)hh >= 64u) continue;  // uniform across wave (h uniform in tile)
      int ww = w + (tap % 3 - 1) * d;
      bool ok = (unsigned)ww < 64u;
      int mrow = (n << 12) + (hh << 6) + (ok ? ww : w);  // safe addr when masked
      const short* arow = xsrc + (size_t)mrow * CST + quad * 8;
      const short* brow = wdr + ((ob + l15) * 9 + tap) * 512 + quad * 8;
#pragma unroll 4
      for (int ks = 0; ks < 16; ++ks) {
        short8 a = *(const short8*)(arow + ks * 32);
        if (!ok) a = z8;
        short8 b = *(const short8*)(brow + ks * 32);
        acc = __builtin_amdgcn_mfma_f32_16x16x32_bf16(a, b, acc, 0, 0, 0);
      }
    }
#pragma unroll
    for (int r = 0; r < 4; ++r) fo[quad * 4 + r][ob + l15] = acc[r];
  }
  __syncthreads();
  // ---------- softmax over 9 taps ----------
  if (tid < 16) {
    int p = tid;
    float mx = fo[p][0];
#pragma unroll
    for (int k = 1; k < 9; ++k) mx = fmaxf(mx, fo[p][k]);
    float s = 0.f, e[9];
#pragma unroll
    for (int k = 0; k < 9; ++k) { e[k] = __expf(fo[p][k] - mx); s += e[k]; }
    float inv = 1.f / s;
#pragma unroll
    for (int k = 0; k < 9; ++k) filt[p][k] = e[k] * inv;
  }
  __syncthreads();
  // ---------- deform bilinear sample; lane = 8 contiguous channels ----------
#pragma unroll 1
  for (int i = 0; i < 8; ++i) {
    int p = wave * 8 + i;
    int m = m0 + p;
    int n = m >> 12, h = (m >> 6) & 63, w = m & 63;
    const short* xb = xsrc + (size_t)(n << 12) * CST + lane * 8;
    float acc[8] = {0.f, 0.f, 0.f, 0.f, 0.f, 0.f, 0.f, 0.f};
#pragma unroll 3
    for (int k = 0; k < 9; ++k) {
      float f = filt[p][k];
      float dy = fo[p][9 + 2 * k];
      float dx = fo[p][10 + 2 * k];
      float ys = (float)(h + (k / 3 - 1) * d) + dy;
      float xs = (float)(w + (k % 3 - 1) * d) + dx;
      float y0f = floorf(ys), x0f = floorf(xs);
      float wy1 = ys - y0f, wx1 = xs - x0f;
      float wy0 = 1.f - wy1, wx0 = 1.f - wx1;
      int y0 = (int)y0f, x0 = (int)x0f;
#pragma unroll
      for (int cy = 0; cy < 2; ++cy) {
#pragma unroll
        for (int cx = 0; cx < 2; ++cx) {
          int yy = y0 + cy, xx = x0 + cx;
          bool v = ((unsigned)yy < 64u) && ((unsigned)xx < 64u);
          float wt = f * (cy ? wy1 : wy0) * (cx ? wx1 : wx0);
          wt = v ? wt : 0.f;
          int row = v ? ((yy << 6) + xx) : 0;
          const short8 vv = *(const short8*)(xb + (size_t)row * CST);
#pragma unroll
          for (int j = 0; j < 8; ++j) acc[j] += wt * bf2f(vv[j]);
        }
      }
    }
    short8 o8;
#pragma unroll
    for (int j = 0; j < 8; ++j) o8[j] = f2bf(acc[j]);
    *(short8*)(dst + (size_t)m * CST + lane * 8) = o8;
  }
}

// ---- 1x1 fuse conv: Y[8192x512] = cat[8192x3072] * wbf^T, bf16 MFMA.
// block 512 thr = 8 waves, block tile 128x128, wave tile 64x32 (4x2 frags).
// Register double-buffered K-loop: loads for k+1 issued before MFMAs on k.
__global__ __launch_bounds__(512) void k_gemm(const short* __restrict__ A,
                                              const short* __restrict__ B,
                                              float* __restrict__ Y) {
  int tid = threadIdx.x;
  int wave = tid >> 6, lane = tid & 63;
  int l15 = lane & 15, quad = lane >> 4;
  int mw = blockIdx.x * 128 + (wave >> 2) * 64;
  int nw = blockIdx.y * 128 + (wave & 3) * 32;
  f32x4 acc[4][2];
  f32x4 zz = {0.f, 0.f, 0.f, 0.f};
#pragma unroll
  for (int i = 0; i < 4; ++i)
#pragma unroll
    for (int j = 0; j < 2; ++j) acc[i][j] = zz;
  const short* ap = A + (size_t)(mw + l15) * CST + quad * 8;
  const short* bp = B + (size_t)(nw + l15) * CST + quad * 8;
  short8 a0[4], b0[2], a1[4], b1[2];
#pragma unroll
  for (int i = 0; i < 4; ++i) a0[i] = *(const short8*)(ap + (size_t)i * 16 * CST);
#pragma unroll
  for (int j = 0; j < 2; ++j) b0[j] = *(const short8*)(bp + (size_t)j * 16 * CST);
  for (int kb = 1; kb <= 96; ++kb) {
    if (kb < 96) {
      int k0 = kb * 32;
#pragma unroll
      for (int i = 0; i < 4; ++i) a1[i] = *(const short8*)(ap + (size_t)i * 16 * CST + k0);
#pragma unroll
      for (int j = 0; j < 2; ++j) b1[j] = *(const short8*)(bp + (size_t)j * 16 * CST + k0);
    }
#pragma unroll
    for (int i = 0; i < 4; ++i)
#pragma unroll
      for (int j = 0; j < 2; ++j)
        acc[i][j] = __builtin_amdgcn_mfma_f32_16x16x32_bf16(a0[i], b0[j], acc[i][j], 0, 0, 0);
#pragma unroll
    for (int i = 0; i < 4; ++i) a0[i] = a1[i];
#pragma unroll
    for (int j = 0; j < 2; ++j) b0[j] = b1[j];
  }
#pragma unroll
  for (int i = 0; i < 4; ++i) {
    int row = mw + i * 16 + quad * 4;
#pragma unroll
    for (int j = 0; j < 2; ++j) {
      int col = nw + j * 16 + l15;
#pragma unroll
      for (int r = 0; r < 4; ++r) Y[(size_t)(row + r) * 512 + col] = acc[i][j][r];
    }
  }
}

// ---- per-channel sum / sumsq over m (atomics after 32-row register accum)
__global__ __launch_bounds__(256) void k_stats(const float* __restrict__ Y,
                                               float* __restrict__ stats) {
  int tid = threadIdx.x;
  int mb = blockIdx.x * 32;
  float s0 = 0.f, q0 = 0.f, s1 = 0.f, q1 = 0.f;
  for (int r = 0; r < 32; ++r) {
    const float* row = Y + (size_t)(mb + r) * 512;
    float v0 = row[tid], v1 = row[tid + 256];
    s0 += v0; q0 += v0 * v0;
    s1 += v1; q1 += v1 * v1;
  }
  atomicAdd(&stats[tid], s0);
  atomicAdd(&stats[tid + 256], s1);
  atomicAdd(&stats[512 + tid], q0);
  atomicAdd(&stats[512 + tid + 256], q1);
}

// ---- normalize + NHWC->NCHW transpose -> d_out
__global__ __launch_bounds__(256) void k_norm(const float* __restrict__ Y,
                                              const float* __restrict__ stats,
                                              const float* __restrict__ gamma,
                                              const float* __restrict__ beta,
                                              float* __restrict__ out) {
  __shared__ float tile[64][65];
  int b = blockIdx.x;
  int cblk = b & 7, h = (b >> 3) & 63, n = b >> 9;
  int c0 = cblk * 64;
  int t = threadIdx.x;
  int cl = t & 63, grp = t >> 6;
  int c = c0 + cl;
  float mean = stats[c] * (1.f / 8192.f);
  float var = stats[512 + c] * (1.f / 8192.f) - mean * mean;
  float Ai = gamma[c] * rsqrtf(var + 1e-5f);
  float Bi = beta[c] - mean * Ai;
  size_t mbase = ((size_t)n * 64 + h) * 64;
#pragma unroll
  for (int i = 0; i < 16; ++i) {
    int w = grp * 16 + i;
    tile[w][cl] = Y[(mbase + w) * 512 + c] * Ai + Bi;
  }
  __syncthreads();
  float* op = out + (((size_t)n * 512 + c0) * 64 + h) * 64;
#pragma unroll
  for (int i = 0; i < 16; ++i) {
    int c2 = grp * 16 + i;
    op[(size_t)c2 * 4096 + cl] = tile[cl][c2];
  }
}

extern "C" void kernel_launch(void* const* d_in, const int* in_sizes, int n_in,
                              void* d_out, int out_size, void* d_ws, size_t ws_size,
                              hipStream_t stream) {
  const float* x  = (const float*)d_in[0];
  const float* w1 = (const float*)d_in[1];
  const float* w2 = (const float*)d_in[2];
  const float* w3 = (const float*)d_in[3];
  const float* w4 = (const float*)d_in[4];
  const float* w5 = (const float*)d_in[5];
  const float* sw = (const float*)d_in[6];
  const float* gamma = (const float*)d_in[7];
  const float* beta  = (const float*)d_in[8];
  float* out = (float*)d_out;

  char* ws = (char*)d_ws;
  // workspace layout (bytes):
  // cat   @ 0        : 8192*3072*2  = 50331648   (bf16, block0 = x NHWC)
  // wbf   @ 50331648 : 512*3072*2   = 3145728
  // wdr   @ 53477376 : 5*32*9*512*2 = 1474560
  // yb    @ 54951936 : 8192*512*4   = 16777216
  // stats @ 71729152 : 1024*4
  short* cat   = (short*)ws;
  short* wbf   = (short*)(ws + 50331648);
  short* wdr   = (short*)(ws + 53477376);
  float* yb    = (float*)(ws + 54951936);
  float* stats = (float*)(ws + 71729152);

  k_prep<<<9028, 256, 0, stream>>>(sw, w1, w2, w3, w4, w5, wbf, wdr, stats);
  k_transx<<<1024, 256, 0, stream>>>(x, cat);
  k_dil<<<2560, 128, 0, stream>>>(cat, cat, wdr);
  k_gemm<<<dim3(64, 4), 512, 0, stream>>>(cat, wbf, yb);
  k_stats<<<256, 256, 0, stream>>>(yb, stats);
  k_norm<<<1024, 256, 0, stream>>>(yb, stats, gamma, beta, out);
}

// Round 3
// 416.514 us; speedup vs baseline: 1.2372x; 1.0734x over previous
//
#include <hip/hip_runtime.h>

typedef short short8 __attribute__((ext_vector_type(8)));
typedef float f32x4 __attribute__((ext_vector_type(4)));

#define CST 3072  // cat row stride (6*512 channels)

__device__ __forceinline__ float bf2f(short s) {
  unsigned u = ((unsigned)(unsigned short)s) << 16;
  return __builtin_bit_cast(float, u);
}
__device__ __forceinline__ short f2bf(float f) {
  unsigned u = __builtin_bit_cast(unsigned, f);
  u = (u + 0x7FFFu + ((u >> 16) & 1u)) >> 16;
  return (short)u;
}

// ---- prep: scale_w -> bf16; w_d reorder (27,512,3,3) -> wdr[di][o pad32][tap][c]; zero stats.
__global__ void k_prep(const float* __restrict__ sw,
                       const float* __restrict__ w1, const float* __restrict__ w2,
                       const float* __restrict__ w3, const float* __restrict__ w4,
                       const float* __restrict__ w5,
                       short* __restrict__ wbf, short* __restrict__ wdr,
                       float* __restrict__ stats) {
  int idx = blockIdx.x * 256 + threadIdx.x;
  const int NS = 512 * 3072;
  const int NW = 5 * 32 * 9 * 512;
  if (idx < NS) {
    wbf[idx] = f2bf(sw[idx]);
  } else if (idx < NS + NW) {
    int j = idx - NS;
    int c = j & 511;
    int t2 = j >> 9;
    int tap = t2 % 9;
    int t3 = t2 / 9;
    int o = t3 & 31;
    int di = t3 >> 5;
    float v = 0.f;
    if (o < 27) {
      const float* wp = (di == 0) ? w1 : (di == 1) ? w2 : (di == 2) ? w3 : (di == 3) ? w4 : w5;
      v = wp[((o * 512 + c) * 3 + tap / 3) * 3 + tap % 3];
    }
    wdr[j] = f2bf(v);
  } else if (idx < NS + NW + 1024) {
    stats[idx - NS - NW] = 0.f;
  }
}

// ---- NCHW fp32 -> NHWC bf16 into cat channel-block 0 (row stride 3072)
__global__ __launch_bounds__(256) void k_transx(const float* __restrict__ x,
                                                short* __restrict__ cat) {
  __shared__ float tile[64][65];
  int b = blockIdx.x;
  int cblk = b & 7, h = (b >> 3) & 63, n = b >> 9;
  int c0 = cblk * 64;
  int t = threadIdx.x;
  int lw = t & 63, grp = t >> 6;
  const float* xp = x + (((size_t)n * 512 + c0) * 64 + h) * 64;
#pragma unroll
  for (int i = 0; i < 16; ++i) {
    int cl = grp * 16 + i;
    tile[cl][lw] = xp[(size_t)cl * 4096 + lw];
  }
  __syncthreads();
  int cl = t & 63;
  size_t mbase = ((size_t)n * 64 + h) * 64;
#pragma unroll
  for (int i = 0; i < 16; ++i) {
    int w = grp * 16 + i;
    cat[(mbase + w) * CST + c0 + cl] = f2bf(tile[cl][w]);
  }
}

// ---- offset conv + softmax: one wave per 16-position tile, all 32 oc.
// Writes foall[p][32]: cols 0..8 = softmaxed filter, 9..26 = offsets.
__global__ __launch_bounds__(256) void k_conv(const short* __restrict__ xsrc,
                                              const short* __restrict__ wdr_all,
                                              float* __restrict__ foall) {
  __shared__ float fo[4][16][33];
  int tid = threadIdx.x;
  int wave = tid >> 6, lane = tid & 63;
  int l15 = lane & 15, quad = lane >> 4;
  int gtile = blockIdx.x * 4 + wave;  // 0..2559
  int di = gtile >> 9;
  int tile = gtile & 511;
  const int DIL[5] = {1, 6, 12, 24, 36};
  int d = DIL[di];
  const short* wdr = wdr_all + di * 32 * 9 * 512;
  int m = tile * 16 + l15;
  int n = m >> 12, h = (m >> 6) & 63, w = m & 63;
  f32x4 acc0 = {0.f, 0.f, 0.f, 0.f}, acc1 = {0.f, 0.f, 0.f, 0.f};
  const short8 z8 = {0, 0, 0, 0, 0, 0, 0, 0};
#pragma unroll
  for (int tap = 0; tap < 9; ++tap) {
    int hh = h + (tap / 3 - 1) * d;
    if ((unsigned)hh >= 64u) continue;  // uniform (h uniform across tile)
    int ww = w + (tap % 3 - 1) * d;
    bool ok = (unsigned)ww < 64u;
    int mrow = (n << 12) + (hh << 6) + (ok ? ww : w);
    const short* arow = xsrc + (size_t)mrow * CST + quad * 8;
    const short* b0p = wdr + (l15 * 9 + tap) * 512 + quad * 8;
    const short* b1p = b0p + 16 * 9 * 512;
#pragma unroll 4
    for (int ks = 0; ks < 16; ++ks) {
      short8 a = *(const short8*)(arow + ks * 32);
      if (!ok) a = z8;
      short8 b0 = *(const short8*)(b0p + ks * 32);
      short8 b1 = *(const short8*)(b1p + ks * 32);
      acc0 = __builtin_amdgcn_mfma_f32_16x16x32_bf16(a, b0, acc0, 0, 0, 0);
      acc1 = __builtin_amdgcn_mfma_f32_16x16x32_bf16(a, b1, acc1, 0, 0, 0);
    }
  }
#pragma unroll
  for (int r = 0; r < 4; ++r) {
    fo[wave][quad * 4 + r][l15] = acc0[r];
    fo[wave][quad * 4 + r][l15 + 16] = acc1[r];
  }
  __syncthreads();
  if (lane < 16) {
    int p = lane;
    float mx = fo[wave][p][0];
#pragma unroll
    for (int k = 1; k < 9; ++k) mx = fmaxf(mx, fo[wave][p][k]);
    float s = 0.f, e[9];
#pragma unroll
    for (int k = 0; k < 9; ++k) { e[k] = __expf(fo[wave][p][k] - mx); s += e[k]; }
    float inv = 1.f / s;
#pragma unroll
    for (int k = 0; k < 9; ++k) fo[wave][p][k] = e[k] * inv;
  }
  __syncthreads();
  float* dst = foall + (size_t)gtile * 512;
#pragma unroll
  for (int j = 0; j < 8; ++j) {
    int flat = j * 64 + lane;
    dst[flat] = fo[wave][flat >> 5][flat & 31];
  }
}

// ---- deform bilinear sample: ONE position per wave; all setup wave-uniform
// (scalar loads of filt/offsets), 36 coalesced 16B loads per wave.
__global__ __launch_bounds__(256, 4) void k_samp(const short* __restrict__ xsrc,
                                                 short* __restrict__ cat,
                                                 const float* __restrict__ foall) {
  int tid = threadIdx.x;
  int wv = __builtin_amdgcn_readfirstlane(tid >> 6);
  int lane = tid & 63;
  int p = blockIdx.x * 4 + wv;  // 0..40959 = di*8192 + m
  int di = p >> 13;
  int m = p & 8191;
  const int DIL[5] = {1, 6, 12, 24, 36};
  int d = DIL[di];
  int n = m >> 12, h = (m >> 6) & 63, w = m & 63;
  const float* fp = foall + (size_t)p * 32;
  const short* xb = xsrc + (size_t)(n << 12) * CST + lane * 8;
  float acc[8] = {0.f, 0.f, 0.f, 0.f, 0.f, 0.f, 0.f, 0.f};
#pragma unroll
  for (int k = 0; k < 9; ++k) {
    float f = fp[k];
    float dy = fp[9 + 2 * k];
    float dx = fp[10 + 2 * k];
    float ys = (float)(h + (k / 3 - 1) * d) + dy;
    float xs = (float)(w + (k % 3 - 1) * d) + dx;
    float y0f = floorf(ys), x0f = floorf(xs);
    float wy1 = ys - y0f, wx1 = xs - x0f;
    float wy0 = 1.f - wy1, wx0 = 1.f - wx1;
    int y0 = (int)y0f, x0 = (int)x0f;
#pragma unroll
    for (int cy = 0; cy < 2; ++cy) {
#pragma unroll
      for (int cx = 0; cx < 2; ++cx) {
        int yy = y0 + cy, xx = x0 + cx;
        bool v = ((unsigned)yy < 64u) && ((unsigned)xx < 64u);
        float wt = f * (cy ? wy1 : wy0) * (cx ? wx1 : wx0);
        wt = v ? wt : 0.f;
        int row = v ? ((yy << 6) + xx) : 0;
        const short8 vv = *(const short8*)(xb + (size_t)row * CST);
#pragma unroll
        for (int j = 0; j < 8; ++j) acc[j] += wt * bf2f(vv[j]);
      }
    }
  }
  short8 o8;
#pragma unroll
  for (int j = 0; j < 8; ++j) o8[j] = f2bf(acc[j]);
  *(short8*)(cat + (size_t)m * CST + 512 * (di + 1) + lane * 8) = o8;
}

// ---- 1x1 fuse conv: Y[8192x512] = cat[8192x3072] * wbf^T, bf16 MFMA.
// 256 thr = 4 waves, block tile 128x64, wave tile 64x32 (4x2 frags).
// Unroll-2 ping-pong (no register copies), grid (64,8) = 512 blocks.
__global__ __launch_bounds__(256) void k_gemm(const short* __restrict__ A,
                                              const short* __restrict__ B,
                                              float* __restrict__ Y) {
  int tid = threadIdx.x;
  int wave = tid >> 6, lane = tid & 63;
  int l15 = lane & 15, quad = lane >> 4;
  int mw = blockIdx.x * 128 + (wave & 1) * 64;
  int nw = blockIdx.y * 64 + (wave >> 1) * 32;
  f32x4 acc[4][2];
  f32x4 zz = {0.f, 0.f, 0.f, 0.f};
#pragma unroll
  for (int i = 0; i < 4; ++i)
#pragma unroll
    for (int j = 0; j < 2; ++j) acc[i][j] = zz;
  const short* ap = A + (size_t)(mw + l15) * CST + quad * 8;
  const short* bp = B + (size_t)(nw + l15) * CST + quad * 8;
  short8 a0[4], b0[2], a1[4], b1[2];
#pragma unroll
  for (int i = 0; i < 4; ++i) a0[i] = *(const short8*)(ap + (size_t)i * 16 * CST);
#pragma unroll
  for (int j = 0; j < 2; ++j) b0[j] = *(const short8*)(bp + (size_t)j * 16 * CST);
#pragma unroll 1
  for (int kb = 0; kb < 96; kb += 2) {
    int k1 = (kb + 1) * 32;
#pragma unroll
    for (int i = 0; i < 4; ++i) a1[i] = *(const short8*)(ap + (size_t)i * 16 * CST + k1);
#pragma unroll
    for (int j = 0; j < 2; ++j) b1[j] = *(const short8*)(bp + (size_t)j * 16 * CST + k1);
#pragma unroll
    for (int i = 0; i < 4; ++i)
#pragma unroll
      for (int j = 0; j < 2; ++j)
        acc[i][j] = __builtin_amdgcn_mfma_f32_16x16x32_bf16(a0[i], b0[j], acc[i][j], 0, 0, 0);
    if (kb + 2 < 96) {
      int k2 = (kb + 2) * 32;
#pragma unroll
      for (int i = 0; i < 4; ++i) a0[i] = *(const short8*)(ap + (size_t)i * 16 * CST + k2);
#pragma unroll
      for (int j = 0; j < 2; ++j) b0[j] = *(const short8*)(bp + (size_t)j * 16 * CST + k2);
    }
#pragma unroll
    for (int i = 0; i < 4; ++i)
#pragma unroll
      for (int j = 0; j < 2; ++j)
        acc[i][j] = __builtin_amdgcn_mfma_f32_16x16x32_bf16(a1[i], b1[j], acc[i][j], 0, 0, 0);
  }
#pragma unroll
  for (int i = 0; i < 4; ++i) {
    int row = mw + i * 16 + quad * 4;
#pragma unroll
    for (int j = 0; j < 2; ++j) {
      int col = nw + j * 16 + l15;
#pragma unroll
      for (int r = 0; r < 4; ++r) Y[(size_t)(row + r) * 512 + col] = acc[i][j][r];
    }
  }
}

// ---- per-channel sum / sumsq over m (atomics after 32-row register accum)
__global__ __launch_bounds__(256) void k_stats(const float* __restrict__ Y,
                                               float* __restrict__ stats) {
  int tid = threadIdx.x;
  int mb = blockIdx.x * 32;
  float s0 = 0.f, q0 = 0.f, s1 = 0.f, q1 = 0.f;
  for (int r = 0; r < 32; ++r) {
    const float* row = Y + (size_t)(mb + r) * 512;
    float v0 = row[tid], v1 = row[tid + 256];
    s0 += v0; q0 += v0 * v0;
    s1 += v1; q1 += v1 * v1;
  }
  atomicAdd(&stats[tid], s0);
  atomicAdd(&stats[tid + 256], s1);
  atomicAdd(&stats[512 + tid], q0);
  atomicAdd(&stats[512 + tid + 256], q1);
}

// ---- normalize + NHWC->NCHW transpose -> d_out
__global__ __launch_bounds__(256) void k_norm(const float* __restrict__ Y,
                                              const float* __restrict__ stats,
                                              const float* __restrict__ gamma,
                                              const float* __restrict__ beta,
                                              float* __restrict__ out) {
  __shared__ float tile[64][65];
  int b = blockIdx.x;
  int cblk = b & 7, h = (b >> 3) & 63, n = b >> 9;
  int c0 = cblk * 64;
  int t = threadIdx.x;
  int cl = t & 63, grp = t >> 6;
  int c = c0 + cl;
  float mean = stats[c] * (1.f / 8192.f);
  float var = stats[512 + c] * (1.f / 8192.f) - mean * mean;
  float Ai = gamma[c] * rsqrtf(var + 1e-5f);
  float Bi = beta[c] - mean * Ai;
  size_t mbase = ((size_t)n * 64 + h) * 64;
#pragma unroll
  for (int i = 0; i < 16; ++i) {
    int w = grp * 16 + i;
    tile[w][cl] = Y[(mbase + w) * 512 + c] * Ai + Bi;
  }
  __syncthreads();
  float* op = out + (((size_t)n * 512 + c0) * 64 + h) * 64;
#pragma unroll
  for (int i = 0; i < 16; ++i) {
    int c2 = grp * 16 + i;
    op[(size_t)c2 * 4096 + cl] = tile[cl][c2];
  }
}

extern "C" void kernel_launch(void* const* d_in, const int* in_sizes, int n_in,
                              void* d_out, int out_size, void* d_ws, size_t ws_size,
                              hipStream_t stream) {
  const float* x  = (const float*)d_in[0];
  const float* w1 = (const float*)d_in[1];
  const float* w2 = (const float*)d_in[2];
  const float* w3 = (const float*)d_in[3];
  const float* w4 = (const float*)d_in[4];
  const float* w5 = (const float*)d_in[5];
  const float* sw = (const float*)d_in[6];
  const float* gamma = (const float*)d_in[7];
  const float* beta  = (const float*)d_in[8];
  float* out = (float*)d_out;

  char* ws = (char*)d_ws;
  // workspace layout (bytes):
  // cat   @ 0        : 8192*3072*2  = 50331648   (bf16, block0 = x NHWC)
  // wbf   @ 50331648 : 512*3072*2   = 3145728
  // wdr   @ 53477376 : 5*32*9*512*2 = 1474560
  // yb    @ 54951936 : 8192*512*4   = 16777216
  // stats @ 71729152 : 1024*4       = 4096
  // foall @ 71733248 : 40960*32*4   = 5242880
  short* cat   = (short*)ws;
  short* wbf   = (short*)(ws + 50331648);
  short* wdr   = (short*)(ws + 53477376);
  float* yb    = (float*)(ws + 54951936);
  float* stats = (float*)(ws + 71729152);
  float* foall = (float*)(ws + 71733248);

  k_prep<<<9028, 256, 0, stream>>>(sw, w1, w2, w3, w4, w5, wbf, wdr, stats);
  k_transx<<<1024, 256, 0, stream>>>(x, cat);
  k_conv<<<640, 256, 0, stream>>>(cat, wdr, foall);
  k_samp<<<10240, 256, 0, stream>>>(cat, cat, foall);
  k_gemm<<<dim3(64, 8), 256, 0, stream>>>(cat, wbf, yb);
  k_stats<<<256, 256, 0, stream>>>(yb, stats);
  k_norm<<<1024, 256, 0, stream>>>(yb, stats, gamma, beta, out);
}

// Round 4
// 248.042 us; speedup vs baseline: 2.0775x; 1.6792x over previous
//
#include <hip/hip_runtime.h>

typedef short short8 __attribute__((ext_vector_type(8)));
typedef float f32x4 __attribute__((ext_vector_type(4)));

#define CST 3072  // cat row stride (6*512 channels)

__device__ __forceinline__ float bf2f(short s) {
  unsigned u = ((unsigned)(unsigned short)s) << 16;
  return __builtin_bit_cast(float, u);
}
__device__ __forceinline__ short f2bf(float f) {
  unsigned u = __builtin_bit_cast(unsigned, f);
  u = (u + 0x7FFFu + ((u >> 16) & 1u)) >> 16;
  return (short)u;
}
__device__ __forceinline__ void gl16(const short* g, short* l) {
  __builtin_amdgcn_global_load_lds(
      (const __attribute__((address_space(1))) unsigned*)g,
      (__attribute__((address_space(3))) unsigned*)l, 16, 0, 0);
}

// ---- prep: scale_w -> bf16; w_d reorder (27,512,3,3) -> wdr[di][tap][oc pad32][c]; zero stats.
__global__ void k_prep(const float* __restrict__ sw,
                       const float* __restrict__ w1, const float* __restrict__ w2,
                       const float* __restrict__ w3, const float* __restrict__ w4,
                       const float* __restrict__ w5,
                       short* __restrict__ wbf, short* __restrict__ wdr,
                       float* __restrict__ stats) {
  int idx = blockIdx.x * 256 + threadIdx.x;
  const int NS = 512 * 3072;
  const int NW = 5 * 9 * 32 * 512;
  if (idx < NS) {
    wbf[idx] = f2bf(sw[idx]);
  } else if (idx < NS + NW) {
    int j = idx - NS;
    int c = j & 511;
    int t2 = j >> 9;
    int oc = t2 & 31;
    int t3 = t2 >> 5;
    int tap = t3 % 9;
    int di = t3 / 9;
    float v = 0.f;
    if (oc < 27) {
      const float* wp = (di == 0) ? w1 : (di == 1) ? w2 : (di == 2) ? w3 : (di == 3) ? w4 : w5;
      v = wp[((oc * 512 + c) * 3 + tap / 3) * 3 + tap % 3];
    }
    wdr[j] = f2bf(v);
  } else if (idx < NS + NW + 1024) {
    stats[idx - NS - NW] = 0.f;
  }
}

// ---- NCHW fp32 -> NHWC bf16 into cat channel-block 0 (row stride 3072)
__global__ __launch_bounds__(256) void k_transx(const float* __restrict__ x,
                                                short* __restrict__ cat) {
  __shared__ float tile[64][65];
  int b = blockIdx.x;
  int cblk = b & 7, h = (b >> 3) & 63, n = b >> 9;
  int c0 = cblk * 64;
  int t = threadIdx.x;
  int lw = t & 63, grp = t >> 6;
  const float* xp = x + (((size_t)n * 512 + c0) * 64 + h) * 64;
#pragma unroll
  for (int i = 0; i < 16; ++i) {
    int cl = grp * 16 + i;
    tile[cl][lw] = xp[(size_t)cl * 4096 + lw];
  }
  __syncthreads();
  int cl = t & 63;
  size_t mbase = ((size_t)n * 64 + h) * 64;
#pragma unroll
  for (int i = 0; i < 16; ++i) {
    int w = grp * 16 + i;
    cat[(mbase + w) * CST + c0 + cl] = f2bf(tile[cl][w]);
  }
}

// ---- offset conv + softmax. Block = 4 tiles (64 pos) of one dilation,
// XCD-affine slab mapping; per-tap B staged in LDS shared by 4 waves.
// wdr layout [di][tap][oc(32)][c(512)]. foall[p][32]: 0..8 filt, 9..26 offs.
__global__ __launch_bounds__(256) void k_conv(const short* __restrict__ xsrc,
                                              const short* __restrict__ wdr_all,
                                              float* __restrict__ foall) {
  __shared__ short Bs[32][516];  // stride 516 shorts -> 2-way bank access (free)
  __shared__ float fo[4][16][33];
  int tid = threadIdx.x;
  int wave = tid >> 6, lane = tid & 63;
  int l15 = lane & 15, quad = lane >> 4;
  int b = blockIdx.x;
  int di = b >> 7;
  int loc = b & 127;
  int tile = (loc & 7) * 64 + (loc >> 3) * 4 + wave;  // xcd*64 + slab*4 + wave
  const int DIL[5] = {1, 6, 12, 24, 36};
  int d = DIL[di];
  int m = tile * 16 + l15;
  int n = m >> 12, h = (m >> 6) & 63, w = m & 63;
  f32x4 acc0 = {0.f, 0.f, 0.f, 0.f}, acc1 = {0.f, 0.f, 0.f, 0.f};
  const short8 z8 = {0, 0, 0, 0, 0, 0, 0, 0};
#pragma unroll 1
  for (int tap = 0; tap < 9; ++tap) {
    __syncthreads();
    const short* src = wdr_all + (size_t)(di * 9 + tap) * 32 * 512;
#pragma unroll
    for (int it = 0; it < 8; ++it) {
      int chunk = it * 256 + tid;
      int oc = chunk >> 6;
      int cc = (chunk & 63) * 8;
      *(short8*)(&Bs[oc][cc]) = *(const short8*)(src + oc * 512 + cc);
    }
    __syncthreads();
    int hh = h + (tap / 3 - 1) * d;
    if ((unsigned)hh >= 64u) continue;  // uniform per wave (h uniform in tile)
    int ww = w + (tap % 3 - 1) * d;
    bool ok = (unsigned)ww < 64u;
    int mrow = (n << 12) + (hh << 6) + (ok ? ww : w);
    const short* arow = xsrc + (size_t)mrow * CST + quad * 8;
#pragma unroll 4
    for (int ks = 0; ks < 16; ++ks) {
      short8 a = *(const short8*)(arow + ks * 32);
      if (!ok) a = z8;
      short8 b0 = *(const short8*)(&Bs[l15][ks * 32 + quad * 8]);
      short8 b1 = *(const short8*)(&Bs[l15 + 16][ks * 32 + quad * 8]);
      acc0 = __builtin_amdgcn_mfma_f32_16x16x32_bf16(a, b0, acc0, 0, 0, 0);
      acc1 = __builtin_amdgcn_mfma_f32_16x16x32_bf16(a, b1, acc1, 0, 0, 0);
    }
  }
#pragma unroll
  for (int r = 0; r < 4; ++r) {
    fo[wave][quad * 4 + r][l15] = acc0[r];
    fo[wave][quad * 4 + r][l15 + 16] = acc1[r];
  }
  __syncthreads();
  if (lane < 16) {
    int p = lane;
    float mx = fo[wave][p][0];
#pragma unroll
    for (int k = 1; k < 9; ++k) mx = fmaxf(mx, fo[wave][p][k]);
    float s = 0.f, e[9];
#pragma unroll
    for (int k = 0; k < 9; ++k) { e[k] = __expf(fo[wave][p][k] - mx); s += e[k]; }
    float inv = 1.f / s;
#pragma unroll
    for (int k = 0; k < 9; ++k) fo[wave][p][k] = e[k] * inv;
  }
  __syncthreads();
  float* dst = foall + ((size_t)di * 512 + tile) * 512;
#pragma unroll
  for (int j = 0; j < 8; ++j) {
    int flat = j * 64 + lane;
    dst[flat] = fo[wave][flat >> 5][flat & 31];
  }
}

// ---- deform bilinear sample: one position per wave, XCD-affine slab order.
__global__ __launch_bounds__(256, 4) void k_samp(const short* __restrict__ xsrc,
                                                 short* __restrict__ cat,
                                                 const float* __restrict__ foall) {
  int tid = threadIdx.x;
  int wv = __builtin_amdgcn_readfirstlane(tid >> 6);
  int lane = tid & 63;
  int b = blockIdx.x;
  int di = b >> 11;
  int loc = b & 2047;
  int m = (loc & 7) * 1024 + (loc >> 3) * 4 + wv;  // xcd*1024 + slab*4 + wave
  const int DIL[5] = {1, 6, 12, 24, 36};
  int d = DIL[di];
  int n = m >> 12, h = (m >> 6) & 63, w = m & 63;
  const float* fp = foall + ((size_t)di * 8192 + m) * 32;
  const short* xb = xsrc + (size_t)(n << 12) * CST + lane * 8;
  float acc[8] = {0.f, 0.f, 0.f, 0.f, 0.f, 0.f, 0.f, 0.f};
#pragma unroll
  for (int k = 0; k < 9; ++k) {
    float f = fp[k];
    float dy = fp[9 + 2 * k];
    float dx = fp[10 + 2 * k];
    float ys = (float)(h + (k / 3 - 1) * d) + dy;
    float xs = (float)(w + (k % 3 - 1) * d) + dx;
    float y0f = floorf(ys), x0f = floorf(xs);
    float wy1 = ys - y0f, wx1 = xs - x0f;
    float wy0 = 1.f - wy1, wx0 = 1.f - wx1;
    int y0 = (int)y0f, x0 = (int)x0f;
#pragma unroll
    for (int cy = 0; cy < 2; ++cy) {
#pragma unroll
      for (int cx = 0; cx < 2; ++cx) {
        int yy = y0 + cy, xx = x0 + cx;
        bool v = ((unsigned)yy < 64u) && ((unsigned)xx < 64u);
        float wt = f * (cy ? wy1 : wy0) * (cx ? wx1 : wx0);
        wt = v ? wt : 0.f;
        int row = v ? ((yy << 6) + xx) : 0;
        const short8 vv = *(const short8*)(xb + (size_t)row * CST);
#pragma unroll
        for (int j = 0; j < 8; ++j) acc[j] += wt * bf2f(vv[j]);
      }
    }
  }
  short8 o8;
#pragma unroll
  for (int j = 0; j < 8; ++j) o8[j] = f2bf(acc[j]);
  *(short8*)(cat + (size_t)m * CST + 512 * (di + 1) + lane * 8) = o8;
}

// ---- 1x1 fuse conv, m97-style LDS GEMM. 128x128 tile, BK=32,
// global_load_lds width 16, K split in 2 (kh) -> 512 blocks (2/CU).
// Y halves stored bf16, summed in stats/norm. XCD-affine block remap.
__global__ __launch_bounds__(256) void k_gemm(const short* __restrict__ A,
                                              const short* __restrict__ B,
                                              short* __restrict__ Y) {
  __shared__ short As[128 * 32];
  __shared__ short Bs[128 * 32];
  int tid = threadIdx.x;
  int wave = tid >> 6, lane = tid & 63;
  int l15 = lane & 15, quad = lane >> 4;
  int bid = blockIdx.x;           // 0..511
  int c = bid & 7, s = bid >> 3;
  int mt = c * 8 + (s >> 3);      // same-XCD blocks share A m-tiles
  int nz = s & 7;
  int nt = nz & 3, kh = nz >> 2;
  int m0 = mt * 128, n0 = nt * 128;
  int kbeg = kh * 1536;
  int wm = (wave >> 1) * 64, wn = (wave & 1) * 64;
  f32x4 acc[4][4];
  f32x4 zz = {0.f, 0.f, 0.f, 0.f};
#pragma unroll
  for (int i = 0; i < 4; ++i)
#pragma unroll
    for (int j = 0; j < 4; ++j) acc[i][j] = zz;
  int srow = tid >> 2, scol = (tid & 3) * 8;
  const short* ag = A + (size_t)(m0 + srow) * CST + kbeg + scol;
  const short* bg = B + (size_t)(n0 + srow) * CST + kbeg + scol;
  short* al = As + tid * 8;
  short* bl = Bs + tid * 8;
#pragma unroll 1
  for (int ks = 0; ks < 48; ++ks) {
    int ko = ks * 32;
    __syncthreads();
    gl16(ag + ko, al);
    gl16(ag + (size_t)64 * CST + ko, al + 2048);
    gl16(bg + ko, bl);
    gl16(bg + (size_t)64 * CST + ko, bl + 2048);
    __syncthreads();
    short8 af[4], bf[4];
#pragma unroll
    for (int i = 0; i < 4; ++i)
      af[i] = *(const short8*)(As + (wm + i * 16 + l15) * 32 + quad * 8);
#pragma unroll
    for (int j = 0; j < 4; ++j)
      bf[j] = *(const short8*)(Bs + (wn + j * 16 + l15) * 32 + quad * 8);
#pragma unroll
    for (int i = 0; i < 4; ++i)
#pragma unroll
      for (int j = 0; j < 4; ++j)
        acc[i][j] = __builtin_amdgcn_mfma_f32_16x16x32_bf16(af[i], bf[j], acc[i][j], 0, 0, 0);
  }
  short* Yp = Y + (size_t)kh * (8192 * 512);
#pragma unroll
  for (int i = 0; i < 4; ++i) {
    int row = m0 + wm + i * 16 + quad * 4;
#pragma unroll
    for (int j = 0; j < 4; ++j) {
      int col = n0 + wn + j * 16 + l15;
#pragma unroll
      for (int r = 0; r < 4; ++r)
        Yp[(size_t)(row + r) * 512 + col] = f2bf(acc[i][j][r]);
    }
  }
}

// ---- per-channel sum / sumsq over m of (y0+y1)
__global__ __launch_bounds__(256) void k_stats(const short* __restrict__ Y,
                                               float* __restrict__ stats) {
  const short* Y1 = Y + (size_t)8192 * 512;
  int tid = threadIdx.x;
  int mb = blockIdx.x * 32;
  float s0 = 0.f, q0 = 0.f, s1 = 0.f, q1 = 0.f;
  for (int r = 0; r < 32; ++r) {
    size_t ro = (size_t)(mb + r) * 512;
    float v0 = bf2f(Y[ro + tid]) + bf2f(Y1[ro + tid]);
    float v1 = bf2f(Y[ro + tid + 256]) + bf2f(Y1[ro + tid + 256]);
    s0 += v0; q0 += v0 * v0;
    s1 += v1; q1 += v1 * v1;
  }
  atomicAdd(&stats[tid], s0);
  atomicAdd(&stats[tid + 256], s1);
  atomicAdd(&stats[512 + tid], q0);
  atomicAdd(&stats[512 + tid + 256], q1);
}

// ---- normalize (y0+y1) + NHWC->NCHW transpose -> d_out
__global__ __launch_bounds__(256) void k_norm(const short* __restrict__ Y,
                                              const float* __restrict__ stats,
                                              const float* __restrict__ gamma,
                                              const float* __restrict__ beta,
                                              float* __restrict__ out) {
  __shared__ float tile[64][65];
  const short* Y1 = Y + (size_t)8192 * 512;
  int b = blockIdx.x;
  int cblk = b & 7, h = (b >> 3) & 63, n = b >> 9;
  int c0 = cblk * 64;
  int t = threadIdx.x;
  int cl = t & 63, grp = t >> 6;
  int c = c0 + cl;
  float mean = stats[c] * (1.f / 8192.f);
  float var = stats[512 + c] * (1.f / 8192.f) - mean * mean;
  float Ai = gamma[c] * rsqrtf(var + 1e-5f);
  float Bi = beta[c] - mean * Ai;
  size_t mbase = ((size_t)n * 64 + h) * 64;
#pragma unroll
  for (int i = 0; i < 16; ++i) {
    int w = grp * 16 + i;
    size_t ro = (mbase + w) * 512 + c;
    tile[w][cl] = (bf2f(Y[ro]) + bf2f(Y1[ro])) * Ai + Bi;
  }
  __syncthreads();
  float* op = out + (((size_t)n * 512 + c0) * 64 + h) * 64;
#pragma unroll
  for (int i = 0; i < 16; ++i) {
    int c2 = grp * 16 + i;
    op[(size_t)c2 * 4096 + cl] = tile[cl][c2];
  }
}

extern "C" void kernel_launch(void* const* d_in, const int* in_sizes, int n_in,
                              void* d_out, int out_size, void* d_ws, size_t ws_size,
                              hipStream_t stream) {
  const float* x  = (const float*)d_in[0];
  const float* w1 = (const float*)d_in[1];
  const float* w2 = (const float*)d_in[2];
  const float* w3 = (const float*)d_in[3];
  const float* w4 = (const float*)d_in[4];
  const float* w5 = (const float*)d_in[5];
  const float* sw = (const float*)d_in[6];
  const float* gamma = (const float*)d_in[7];
  const float* beta  = (const float*)d_in[8];
  float* out = (float*)d_out;

  char* ws = (char*)d_ws;
  // workspace layout (bytes):
  // cat   @ 0        : 8192*3072*2    = 50331648   (bf16, block0 = x NHWC)
  // wbf   @ 50331648 : 512*3072*2     = 3145728
  // wdr   @ 53477376 : 5*9*32*512*2   = 1474560
  // yb    @ 54951936 : 2*8192*512*2   = 16777216   (two bf16 K-halves)
  // stats @ 71729152 : 1024*4         = 4096
  // foall @ 71733248 : 40960*32*4     = 5242880
  short* cat   = (short*)ws;
  short* wbf   = (short*)(ws + 50331648);
  short* wdr   = (short*)(ws + 53477376);
  short* yb    = (short*)(ws + 54951936);
  float* stats = (float*)(ws + 71729152);
  float* foall = (float*)(ws + 71733248);

  k_prep<<<9028, 256, 0, stream>>>(sw, w1, w2, w3, w4, w5, wbf, wdr, stats);
  k_transx<<<1024, 256, 0, stream>>>(x, cat);
  k_conv<<<640, 256, 0, stream>>>(cat, wdr, foall);
  k_samp<<<10240, 256, 0, stream>>>(cat, cat, foall);
  k_gemm<<<512, 256, 0, stream>>>(cat, wbf, yb);
  k_stats<<<256, 256, 0, stream>>>(yb, stats);
  k_norm<<<1024, 256, 0, stream>>>(yb, stats, gamma, beta, out);
}